// Round 1
// baseline (2352.125 us; speedup 1.0000x reference)
//
#include <hip/hip_runtime.h>
#include <hip/hip_bf16.h>
#include <math.h>

typedef short bf16x8 __attribute__((ext_vector_type(8)));
typedef float f32x4 __attribute__((ext_vector_type(4)));

#define E_ 8
#define H_ 2048
#define I_ 2048
#define F_ 4096
#define M_ 512

__device__ __forceinline__ unsigned short f2bf(float f) {
  union { float f; unsigned u; } v; v.f = f;
  unsigned r = v.u + 0x7fffu + ((v.u >> 16) & 1u);
  return (unsigned short)(r >> 16);
}

// MODE 0: act[c,e] (512x2048 bf16, ws) = silu/gate( X[b,e](512x2048 f32) @ W1[e](2048x4096 f32) + b1 )
// MODE 1: out[e,c] (512x2048 f32)      = act[c,e](bf16) @ W2[e](2048x2048 f32) + b2
template<int MODE>
__global__ __launch_bounds__(256) void moe_gemm(
    const float* __restrict__ af,          // MODE0: dispatched
    const unsigned short* __restrict__ ab, // MODE1: activated (bf16)
    const float* __restrict__ w,           // w1 / w2
    const float* __restrict__ bias,        // w1_bias / w2_bias
    unsigned short* __restrict__ actout,   // MODE0 output
    float* __restrict__ dout)              // MODE1 output
{
  // A: row-major [128][64] bf16, byte addr = row*128 + k*2, XOR-swizzled by ((row&7)<<4)
  // B: octet layout, 16B slot = koct*128 + slot  (slot: de-interleaved f-col for MODE0, n for MODE1)
  __shared__ unsigned short As[128 * 64];
  __shared__ unsigned short Bs[8 * 128 * 8];
  char* Ab = (char*)As;
  char* Bb = (char*)Bs;

  const int tid  = threadIdx.x;
  const int lane = tid & 63;
  const int wid  = tid >> 6;

  int be, tm, tn;
  if (MODE == 0) { be = blockIdx.x >> 7; tm = (blockIdx.x >> 5) & 3; tn = blockIdx.x & 31; }
  else           { be = blockIdx.x >> 6; tm = (blockIdx.x >> 4) & 3; tn = blockIdx.x & 15; }
  const int c  = be >> 3;            // = b (A==1) for MODE0, = c for MODE1
  const int e  = be & 7;
  const int m0 = tm * 128;
  const int n0 = (MODE == 0) ? tn * 64 : tn * 128;   // i0 or h0

  f32x4 acc[2][8];
  #pragma unroll
  for (int im = 0; im < 2; ++im)
    #pragma unroll
    for (int in = 0; in < 8; ++in)
      acc[im][in] = (f32x4){0.f, 0.f, 0.f, 0.f};

  const int arow = tid >> 3;   // 0..31
  const int aoct = tid & 7;    // 0..7
  const int bq   = tid & 127;  // 0..127
  const int bko  = tid >> 7;   // 0..1

  const size_t a_row_base = (size_t)((c * E_ + e) * M_ + m0);

  for (int k0 = 0; k0 < H_; k0 += 64) {
    // ---- stage A tile (128 rows x 64 k), fp32->bf16 (MODE0) or bf16 copy (MODE1) ----
    #pragma unroll
    for (int p = 0; p < 4; ++p) {
      const int row = p * 32 + arow;
      bf16x8 pk;
      if (MODE == 0) {
        const float* src = af + (a_row_base + row) * H_ + k0 + aoct * 8;
        float4 f0 = *(const float4*)src;
        float4 f1 = *(const float4*)(src + 4);
        pk[0] = (short)f2bf(f0.x); pk[1] = (short)f2bf(f0.y);
        pk[2] = (short)f2bf(f0.z); pk[3] = (short)f2bf(f0.w);
        pk[4] = (short)f2bf(f1.x); pk[5] = (short)f2bf(f1.y);
        pk[6] = (short)f2bf(f1.z); pk[7] = (short)f2bf(f1.w);
      } else {
        pk = *(const bf16x8*)(ab + (a_row_base + row) * I_ + k0 + aoct * 8);
      }
      int ad = row * 128 + aoct * 16;
      ad ^= (row & 7) << 4;
      *(bf16x8*)(Ab + ad) = pk;
    }
    // ---- stage B tile (64 k x 128 cols) via k-column loads (8 consecutive k per thread) ----
    #pragma unroll
    for (int p = 0; p < 4; ++p) {
      const int koct = p * 2 + bko;   // 0..7
      bf16x8 pk;
      int slot;
      if (MODE == 0) {
        // f-columns [2*n0, 2*n0+128); de-interleave: even f (gate) -> slot q/2, odd f (up) -> 64 + q/2
        const float* src = w + ((size_t)(e * H_ + k0 + koct * 8)) * F_ + 2 * n0 + bq;
        #pragma unroll
        for (int j = 0; j < 8; ++j) pk[j] = (short)f2bf(src[(size_t)j * F_]);
        slot = (bq >> 1) + (bq & 1) * 64;
      } else {
        const float* src = w + ((size_t)(e * I_ + k0 + koct * 8)) * H_ + n0 + bq;
        #pragma unroll
        for (int j = 0; j < 8; ++j) pk[j] = (short)f2bf(src[(size_t)j * H_]);
        slot = bq;
      }
      *(bf16x8*)(Bb + (koct * 128 + slot) * 16) = pk;
    }
    __syncthreads();
    // ---- MFMA: wave computes 32 rows x 128 slot-cols ----
    #pragma unroll
    for (int ks = 0; ks < 2; ++ks) {
      bf16x8 a0, a1, bfr[8];
      {
        const int kloc = ks * 32 + (lane >> 4) * 8;
        const int r0 = wid * 32 + (lane & 15);
        int ad0 = r0 * 128 + kloc * 2; ad0 ^= (r0 & 7) << 4;
        a0 = *(const bf16x8*)(Ab + ad0);
        const int r1 = r0 + 16;
        int ad1 = r1 * 128 + kloc * 2; ad1 ^= (r1 & 7) << 4;
        a1 = *(const bf16x8*)(Ab + ad1);
      }
      const int oct = ks * 4 + (lane >> 4);
      #pragma unroll
      for (int in = 0; in < 8; ++in) {
        const int col = in * 16 + (lane & 15);
        bfr[in] = *(const bf16x8*)(Bb + (oct * 128 + col) * 16);
      }
      #pragma unroll
      for (int in = 0; in < 8; ++in) {
        acc[0][in] = __builtin_amdgcn_mfma_f32_16x16x32_bf16(a0, bfr[in], acc[0][in], 0, 0, 0);
        acc[1][in] = __builtin_amdgcn_mfma_f32_16x16x32_bf16(a1, bfr[in], acc[1][in], 0, 0, 0);
      }
    }
    __syncthreads();
  }

  // ---- epilogue ----
  const int rb = m0 + wid * 32 + ((lane >> 4) * 4);
  if (MODE == 0) {
    #pragma unroll
    for (int in = 0; in < 4; ++in) {
      const int icol = n0 + in * 16 + (lane & 15);
      const float bg = bias[e * F_ + 2 * icol];
      const float bu = bias[e * F_ + 2 * icol + 1];
      #pragma unroll
      for (int im = 0; im < 2; ++im) {
        #pragma unroll
        for (int r = 0; r < 4; ++r) {
          const int row = rb + im * 16 + r;
          const float g = acc[im][in][r] + bg;
          const float u = acc[im][in + 4][r] + bu;
          const float val = (g / (1.f + __expf(-g))) * u;   // silu(g)*u
          actout[((size_t)((c * E_ + e) * M_) + row) * I_ + icol] = f2bf(val);
        }
      }
    }
  } else {
    #pragma unroll
    for (int in = 0; in < 8; ++in) {
      const int h = n0 + in * 16 + (lane & 15);
      const float bb = bias[e * H_ + h];
      #pragma unroll
      for (int im = 0; im < 2; ++im) {
        #pragma unroll
        for (int r = 0; r < 4; ++r) {
          const int row = rb + im * 16 + r;
          dout[(size_t)e * (8 * (size_t)M_ * H_) + ((size_t)(c * M_ + row)) * H_ + h] =
              acc[im][in][r] + bb;
        }
      }
    }
  }
}

extern "C" void kernel_launch(void* const* d_in, const int* in_sizes, int n_in,
                              void* d_out, int out_size, void* d_ws, size_t ws_size,
                              hipStream_t stream) {
  const float* disp = (const float*)d_in[0];
  const float* w1   = (const float*)d_in[1];
  const float* w1b  = (const float*)d_in[2];
  const float* w2   = (const float*)d_in[3];
  const float* w2b  = (const float*)d_in[4];
  // d_in[5] sparsity_remap (all zeros, unused by reference), d_in[6]=BD, d_in[7]=S

  unsigned short* act = (unsigned short*)d_ws;  // 8*8*512*2048 bf16 = 134 MB
  float* out = (float*)d_out;

  // GEMM1 + bias + silu*up -> act (bf16)
  moe_gemm<0><<<8192, 256, 0, stream>>>(disp, nullptr, w1, w1b, act, nullptr);
  // GEMM2 + bias -> out (fp32, transposed (e, c*M+m, h))
  moe_gemm<1><<<4096, 256, 0, stream>>>(nullptr, act, w2, w2b, nullptr, out);
}

// Round 2
// 1910.156 us; speedup vs baseline: 1.2314x; 1.2314x over previous
//
#include <hip/hip_runtime.h>
#include <hip/hip_bf16.h>
#include <math.h>

typedef short bf16x8 __attribute__((ext_vector_type(8)));
typedef float f32x4 __attribute__((ext_vector_type(4)));

#define E_ 8
#define H_ 2048
#define I_ 2048
#define F_ 4096
#define M_ 512

__device__ __forceinline__ unsigned short f2bf(float f) {
  union { float f; unsigned u; } v; v.f = f;
  unsigned r = v.u + 0x7fffu + ((v.u >> 16) & 1u);
  return (unsigned short)(r >> 16);
}

__device__ __forceinline__ void gload16(const void* g, void* l) {
  __builtin_amdgcn_global_load_lds(
      (const __attribute__((address_space(1))) void*)g,
      (__attribute__((address_space(3))) void*)l, 16, 0, 0);
}

// ---------------- converts ----------------

// elementwise f32 -> bf16, 8 elems/thread
__global__ __launch_bounds__(256) void conv_x(const float* __restrict__ x,
                                              unsigned short* __restrict__ xb) {
  const size_t i = (size_t)blockIdx.x * 256 + threadIdx.x;
  const float4 a = *(const float4*)(x + i * 8);
  const float4 b = *(const float4*)(x + i * 8 + 4);
  bf16x8 o;
  o[0] = (short)f2bf(a.x); o[1] = (short)f2bf(a.y);
  o[2] = (short)f2bf(a.z); o[3] = (short)f2bf(a.w);
  o[4] = (short)f2bf(b.x); o[5] = (short)f2bf(b.y);
  o[6] = (short)f2bf(b.z); o[7] = (short)f2bf(b.w);
  *(bf16x8*)(xb + i * 8) = o;
}

// w [e][K=2048][F] f32  ->  wT [e][F][K] bf16   (64x64 LDS-tiled transpose)
__global__ __launch_bounds__(256) void conv_transpose(const float* __restrict__ w,
                                                      unsigned short* __restrict__ wT,
                                                      int F) {
  __shared__ unsigned short T[64 * 72];   // [f_local][k + pad], row pitch 144B (16B mult)
  const int t = threadIdx.x;
  int b = blockIdx.x;
  const int nf = F >> 6;
  const int f0 = (b % nf) << 6; b /= nf;
  const int k0 = (b & 31) << 6;
  const int e  = b >> 5;

  const int kr = t >> 4, fq = t & 15;
  #pragma unroll
  for (int j = 0; j < 4; ++j) {
    const int k = j * 16 + kr;
    const float4 v = *(const float4*)(w + (size_t)(e * H_ + k0 + k) * F + f0 + fq * 4);
    T[(fq * 4 + 0) * 72 + k] = f2bf(v.x);
    T[(fq * 4 + 1) * 72 + k] = f2bf(v.y);
    T[(fq * 4 + 2) * 72 + k] = f2bf(v.z);
    T[(fq * 4 + 3) * 72 + k] = f2bf(v.w);
  }
  __syncthreads();
  #pragma unroll
  for (int j = 0; j < 2; ++j) {
    const int id = j * 256 + t;
    const int f = id >> 3, koct = id & 7;
    bf16x8 v = *(const bf16x8*)(&T[f * 72 + koct * 8]);
    *(bf16x8*)(wT + (size_t)(e * F + f0 + f) * H_ + k0 + koct * 8) = v;
  }
}

// ---------------- fast GEMMs (all-bf16, global_load_lds staged) ----------------
// MODE 0: act[c,e] (512x2048 bf16) = silu/gate( Xbf @ w1T^T + b1 ),  w1T [e][4096][2048]
// MODE 1: out[e,c] (512x2048 f32)  = act @ w2T^T + b2,              w2T [e][2048][2048]
// LDS: A [row 0..127][octsw 0..7] 16B chunks, swizzle octsw = oct ^ (row&7); B same on slots.
template<int MODE>
__global__ __launch_bounds__(256) void moe_gemm_fast(
    const unsigned short* __restrict__ abf,
    const unsigned short* __restrict__ wT,
    const float* __restrict__ bias,
    unsigned short* __restrict__ actout,
    float* __restrict__ dout) {
  __shared__ unsigned short As[8192];   // 16 KB
  __shared__ unsigned short Bs[8192];   // 16 KB
  char* Ab = (char*)As;
  char* Bb = (char*)Bs;

  const int tid  = threadIdx.x;
  const int lane = tid & 63;
  const int wid  = tid >> 6;
  const int l15  = lane & 15, lh = lane >> 4;

  const int L = blockIdx.x;
  int e, c, tm, tn, n0, Fdim;
  if (MODE == 0) {
    const int orig = (L & 7) * 1024 + (L >> 3);   // expert-per-XCD swizzle
    e = orig >> 10; c = (orig >> 7) & 7; tm = (orig >> 5) & 3; tn = orig & 31;
    n0 = tn * 64; Fdim = F_;
  } else {
    const int orig = (L & 7) * 512 + (L >> 3);
    e = orig >> 9; c = (orig >> 6) & 7; tm = (orig >> 4) & 3; tn = orig & 15;
    n0 = tn * 128; Fdim = H_;
  }
  const int m0 = tm * 128;
  const size_t a_row_base = (size_t)((c * E_ + e) * M_ + m0);

  // per-thread staging source pointers (k0 added in loop)
  const unsigned short* pA[4];
  const unsigned short* pB[4];
  #pragma unroll
  for (int j = 0; j < 4; ++j) {
    const int chunk = wid * 4 + j;
    const int row = chunk * 8 + (lane >> 3);
    const int aoct = (lane & 7) ^ (row & 7);
    pA[j] = abf + (a_row_base + row) * H_ + aoct * 8;
    const int slot = row;                      // same index pattern
    const int boct = (lane & 7) ^ (slot & 7);
    int fg;
    if (MODE == 0) fg = (slot < 64) ? 2 * (n0 + slot) : 2 * (n0 + slot - 64) + 1;
    else           fg = n0 + slot;
    pB[j] = wT + (size_t)(e * Fdim + fg) * H_ + boct * 8;
  }

  f32x4 acc[2][8];
  #pragma unroll
  for (int im = 0; im < 2; ++im)
    #pragma unroll
    for (int in = 0; in < 8; ++in)
      acc[im][in] = (f32x4){0.f, 0.f, 0.f, 0.f};

  for (int k0 = 0; k0 < H_; k0 += 64) {
    #pragma unroll
    for (int j = 0; j < 4; ++j) {
      const int chunk = wid * 4 + j;
      gload16(pA[j] + k0, Ab + chunk * 1024);
      gload16(pB[j] + k0, Bb + chunk * 1024);
    }
    __syncthreads();   // compiler drains vmcnt(0) here
    #pragma unroll
    for (int ks = 0; ks < 2; ++ks) {
      const int oct = ks * 4 + lh;
      const int r0 = wid * 32 + l15;
      const int sw = (oct ^ (r0 & 7)) << 4;    // r0 and r0+16 share (row&7)
      bf16x8 a0 = *(const bf16x8*)(Ab + r0 * 128 + sw);
      bf16x8 a1 = *(const bf16x8*)(Ab + (r0 + 16) * 128 + sw);
      #pragma unroll
      for (int in = 0; in < 8; ++in) {
        const int col = in * 16 + l15;
        bf16x8 b = *(const bf16x8*)(Bb + col * 128 + ((oct ^ (col & 7)) << 4));
        acc[0][in] = __builtin_amdgcn_mfma_f32_16x16x32_bf16(a0, b, acc[0][in], 0, 0, 0);
        acc[1][in] = __builtin_amdgcn_mfma_f32_16x16x32_bf16(a1, b, acc[1][in], 0, 0, 0);
      }
    }
    __syncthreads();
  }

  const int rb = m0 + wid * 32 + lh * 4;
  if (MODE == 0) {
    #pragma unroll
    for (int in = 0; in < 4; ++in) {
      const int icol = n0 + in * 16 + l15;
      const float bg = bias[e * F_ + 2 * icol];
      const float bu = bias[e * F_ + 2 * icol + 1];
      #pragma unroll
      for (int im = 0; im < 2; ++im) {
        #pragma unroll
        for (int r = 0; r < 4; ++r) {
          const int row = rb + im * 16 + r;
          const float g = acc[im][in][r] + bg;
          const float u = acc[im][in + 4][r] + bu;
          const float val = (g / (1.f + __expf(-g))) * u;
          actout[((size_t)((c * E_ + e) * M_) + row) * I_ + icol] = f2bf(val);
        }
      }
    }
  } else {
    #pragma unroll
    for (int in = 0; in < 8; ++in) {
      const int h = n0 + in * 16 + l15;
      const float bb = bias[e * H_ + h];
      #pragma unroll
      for (int im = 0; im < 2; ++im) {
        #pragma unroll
        for (int r = 0; r < 4; ++r) {
          const int row = rb + im * 16 + r;
          dout[(size_t)e * (8 * (size_t)M_ * H_) + ((size_t)(c * M_ + row)) * H_ + h] =
              acc[im][in][r] + bb;
        }
      }
    }
  }
}

// ---------------- round-1 fallback (validated) ----------------
template<int MODE>
__global__ __launch_bounds__(256) void moe_gemm(
    const float* __restrict__ af,
    const unsigned short* __restrict__ ab,
    const float* __restrict__ w,
    const float* __restrict__ bias,
    unsigned short* __restrict__ actout,
    float* __restrict__ dout) {
  __shared__ unsigned short As[128 * 64];
  __shared__ unsigned short Bs[8 * 128 * 8];
  char* Ab = (char*)As;
  char* Bb = (char*)Bs;
  const int tid  = threadIdx.x;
  const int lane = tid & 63;
  const int wid  = tid >> 6;
  int be, tm, tn;
  if (MODE == 0) { be = blockIdx.x >> 7; tm = (blockIdx.x >> 5) & 3; tn = blockIdx.x & 31; }
  else           { be = blockIdx.x >> 6; tm = (blockIdx.x >> 4) & 3; tn = blockIdx.x & 15; }
  const int c  = be >> 3;
  const int e  = be & 7;
  const int m0 = tm * 128;
  const int n0 = (MODE == 0) ? tn * 64 : tn * 128;
  f32x4 acc[2][8];
  #pragma unroll
  for (int im = 0; im < 2; ++im)
    #pragma unroll
    for (int in = 0; in < 8; ++in)
      acc[im][in] = (f32x4){0.f, 0.f, 0.f, 0.f};
  const int arow = tid >> 3;
  const int aoct = tid & 7;
  const int bq   = tid & 127;
  const int bko  = tid >> 7;
  const size_t a_row_base = (size_t)((c * E_ + e) * M_ + m0);
  for (int k0 = 0; k0 < H_; k0 += 64) {
    #pragma unroll
    for (int p = 0; p < 4; ++p) {
      const int row = p * 32 + arow;
      bf16x8 pk;
      if (MODE == 0) {
        const float* src = af + (a_row_base + row) * H_ + k0 + aoct * 8;
        float4 f0 = *(const float4*)src;
        float4 f1 = *(const float4*)(src + 4);
        pk[0] = (short)f2bf(f0.x); pk[1] = (short)f2bf(f0.y);
        pk[2] = (short)f2bf(f0.z); pk[3] = (short)f2bf(f0.w);
        pk[4] = (short)f2bf(f1.x); pk[5] = (short)f2bf(f1.y);
        pk[6] = (short)f2bf(f1.z); pk[7] = (short)f2bf(f1.w);
      } else {
        pk = *(const bf16x8*)(ab + (a_row_base + row) * I_ + k0 + aoct * 8);
      }
      int ad = row * 128 + aoct * 16;
      ad ^= (row & 7) << 4;
      *(bf16x8*)(Ab + ad) = pk;
    }
    #pragma unroll
    for (int p = 0; p < 4; ++p) {
      const int koct = p * 2 + bko;
      bf16x8 pk;
      int slot;
      if (MODE == 0) {
        const float* src = w + ((size_t)(e * H_ + k0 + koct * 8)) * F_ + 2 * n0 + bq;
        #pragma unroll
        for (int j = 0; j < 8; ++j) pk[j] = (short)f2bf(src[(size_t)j * F_]);
        slot = (bq >> 1) + (bq & 1) * 64;
      } else {
        const float* src = w + ((size_t)(e * I_ + k0 + koct * 8)) * H_ + n0 + bq;
        #pragma unroll
        for (int j = 0; j < 8; ++j) pk[j] = (short)f2bf(src[(size_t)j * H_]);
        slot = bq;
      }
      *(bf16x8*)(Bb + (koct * 128 + slot) * 16) = pk;
    }
    __syncthreads();
    #pragma unroll
    for (int ks = 0; ks < 2; ++ks) {
      bf16x8 a0, a1, bfr[8];
      {
        const int kloc = ks * 32 + (lane >> 4) * 8;
        const int r0 = wid * 32 + (lane & 15);
        int ad0 = r0 * 128 + kloc * 2; ad0 ^= (r0 & 7) << 4;
        a0 = *(const bf16x8*)(Ab + ad0);
        const int r1 = r0 + 16;
        int ad1 = r1 * 128 + kloc * 2; ad1 ^= (r1 & 7) << 4;
        a1 = *(const bf16x8*)(Ab + ad1);
      }
      const int oct = ks * 4 + (lane >> 4);
      #pragma unroll
      for (int in = 0; in < 8; ++in) {
        const int col = in * 16 + (lane & 15);
        bfr[in] = *(const bf16x8*)(Bb + (oct * 128 + col) * 16);
      }
      #pragma unroll
      for (int in = 0; in < 8; ++in) {
        acc[0][in] = __builtin_amdgcn_mfma_f32_16x16x32_bf16(a0, bfr[in], acc[0][in], 0, 0, 0);
        acc[1][in] = __builtin_amdgcn_mfma_f32_16x16x32_bf16(a1, bfr[in], acc[1][in], 0, 0, 0);
      }
    }
    __syncthreads();
  }
  const int rb = m0 + wid * 32 + ((lane >> 4) * 4);
  if (MODE == 0) {
    #pragma unroll
    for (int in = 0; in < 4; ++in) {
      const int icol = n0 + in * 16 + (lane & 15);
      const float bg = bias[e * F_ + 2 * icol];
      const float bu = bias[e * F_ + 2 * icol + 1];
      #pragma unroll
      for (int im = 0; im < 2; ++im) {
        #pragma unroll
        for (int r = 0; r < 4; ++r) {
          const int row = rb + im * 16 + r;
          const float g = acc[im][in][r] + bg;
          const float u = acc[im][in + 4][r] + bu;
          const float val = (g / (1.f + __expf(-g))) * u;
          actout[((size_t)((c * E_ + e) * M_) + row) * I_ + icol] = f2bf(val);
        }
      }
    }
  } else {
    #pragma unroll
    for (int in = 0; in < 8; ++in) {
      const int h = n0 + in * 16 + (lane & 15);
      const float bb = bias[e * H_ + h];
      #pragma unroll
      for (int im = 0; im < 2; ++im) {
        #pragma unroll
        for (int r = 0; r < 4; ++r) {
          const int row = rb + im * 16 + r;
          dout[(size_t)e * (8 * (size_t)M_ * H_) + ((size_t)(c * M_ + row)) * H_ + h] =
              acc[im][in][r] + bb;
        }
      }
    }
  }
}

extern "C" void kernel_launch(void* const* d_in, const int* in_sizes, int n_in,
                              void* d_out, int out_size, void* d_ws, size_t ws_size,
                              hipStream_t stream) {
  const float* disp = (const float*)d_in[0];
  const float* w1   = (const float*)d_in[1];
  const float* w1b  = (const float*)d_in[2];
  const float* w2   = (const float*)d_in[3];
  const float* w2b  = (const float*)d_in[4];
  float* out = (float*)d_out;

  const size_t ELEMS = (size_t)64 * 512 * 2048;           // 67,108,864
  const size_t need = ELEMS * 2 * 3 + ELEMS;              // Xbf+act+w1T (2B each) + w2T (half)
  // = 134MB*3 + 67MB = 470 MB
  if (ws_size >= need) {
    unsigned short* Xbf = (unsigned short*)d_ws;
    unsigned short* act = Xbf + ELEMS;
    unsigned short* w1T = act + ELEMS;
    unsigned short* w2T = w1T + ELEMS;
    conv_x<<<32768, 256, 0, stream>>>(disp, Xbf);
    conv_transpose<<<16384, 256, 0, stream>>>(w1, w1T, F_);
    conv_transpose<<<8192, 256, 0, stream>>>(w2, w2T, H_);
    moe_gemm_fast<0><<<8192, 256, 0, stream>>>(Xbf, w1T, w1b, act, nullptr);
    moe_gemm_fast<1><<<4096, 256, 0, stream>>>(act, w2T, w2b, nullptr, out);
  } else {
    unsigned short* act = (unsigned short*)d_ws;
    moe_gemm<0><<<8192, 256, 0, stream>>>(disp, nullptr, w1, w1b, act, nullptr);
    moe_gemm<1><<<4096, 256, 0, stream>>>(nullptr, act, w2, w2b, nullptr, out);
  }
}